// Round 6
// baseline (111.010 us; speedup 1.0000x reference)
//
#include <hip/hip_runtime.h>
#include <math.h>

#define NP 30
#define NX 13
#define ROWS 256

typedef float v4f __attribute__((ext_vector_type(4)));

__global__ __launch_bounds__(ROWS) void t1d_kernel(
    const float* __restrict__ x,
    const float* __restrict__ params,
    const float* __restrict__ CHO,
    const float* __restrict__ insulin_u,
    const float* __restrict__ last_Qsto,
    const float* __restrict__ last_foodtaken,
    float* __restrict__ out,
    int n)
{
    // Read side: block's contiguous params/x chunks staged via coalesced
    // float4 loads (11 VMEM insts/thread instead of 47 scalar ones).
    // Write side: outputs staged in lds_x (reused), written back as
    // full-line coalesced NON-TEMPORAL float4 (R5's proven win: ideal
    // WRITE_SIZE, no L2/L3 pollution of replay-resident inputs).
    __shared__ float lds_p[ROWS * NP];   // 30720 B
    __shared__ float lds_x[ROWS * NX];   // 13312 B (inputs, then outputs)

    const int tid = threadIdx.x;
    const long long blockStart = (long long)blockIdx.x * ROWS;
    const long long rem = (long long)n - blockStart;
    if (rem <= 0) return;
    const int nrows = rem < ROWS ? (int)rem : ROWS;

    // ---- stage params & x with fully-coalesced float4 loads ----
    {
        const float* srcp = params + blockStart * NP;   // 30720B*blockIdx -> 16B aligned
        const int totp = nrows * NP;
        const int pf4 = totp >> 2;
        const v4f* s4 = (const v4f*)srcp;
        v4f* d4 = (v4f*)lds_p;
        for (int idx = tid; idx < pf4; idx += ROWS) d4[idx] = s4[idx];
        for (int g = (pf4 << 2) + tid; g < totp; g += ROWS) lds_p[g] = srcp[g];

        const float* srcx = x + blockStart * NX;        // 13312B*blockIdx -> 16B aligned
        const int totx = nrows * NX;
        const int xf4 = totx >> 2;
        const v4f* sx4 = (const v4f*)srcx;
        v4f* dx4 = (v4f*)lds_x;
        for (int idx = tid; idx < xf4; idx += ROWS) dx4[idx] = sx4[idx];
        for (int g = (xf4 << 2) + tid; g < totx; g += ROWS) lds_x[g] = srcx[g];
    }
    __syncthreads();

    if (tid < nrows) {
        const long long i = blockStart + tid;

        const float* p = lds_p + tid * NP;   // stride-30: ~4 lanes/bank, cheap
        float kmax = p[0],  kmin = p[1],  b    = p[2],  d_   = p[3];
        float kabs = p[4],  f    = p[5],  BW   = p[6],  kp1  = p[7];
        float kp2  = p[8],  kp3  = p[9],  Fsnc = p[10], ke1  = p[11];
        float ke2  = p[12], k1   = p[13], k2   = p[14], Vm0  = p[15];
        float Vmx  = p[16], Km0  = p[17], m1   = p[18], m2   = p[19];
        float m4   = p[20], m30  = p[21], ka1  = p[22], ka2  = p[23];
        float kd   = p[24], Vi   = p[25], p2u  = p[26], Ib   = p[27];
        float ki   = p[28], ksc  = p[29];

        const float* xr = lds_x + tid * NX;  // stride-13: conflict-free
        float x0 = xr[0], x1 = xr[1], x2 = xr[2], x3 = xr[3], x4 = xr[4];
        float x5 = xr[5], x6 = xr[6], x7 = xr[7], x8 = xr[8], x9 = xr[9];
        float x10 = xr[10], x11 = xr[11], x12 = xr[12];

        float d       = CHO[i] * 1000.0f;               // stride-1 coalesced
        float insulin = insulin_u[i] * 6000.0f / BW;

        float qsto = x0 + x1;
        float Dbar = last_Qsto[i] + last_foodtaken[i];  // stride-1 coalesced
        bool has_food = Dbar > 0.0f;
        float Dbar_safe = has_food ? Dbar : 1.0f;
        float aa = 2.5f / (1.0f - b) / Dbar_safe;
        float cc = 2.5f / d_ / Dbar_safe;
        float kgut_eating = kmin + (kmax - kmin) * 0.5f *
            (tanhf(aa * (qsto - b * Dbar)) - tanhf(cc * (qsto - d_ * Dbar)) + 2.0f);
        float kgut = has_food ? kgut_eating : kmax;

        float o0 = -kmax * x0 + d;
        float o1 = kmax * x0 - x1 * kgut;
        float o2 = kgut * x1 - kabs * x2;

        float Rat  = f * kabs * x2 / BW;
        float EGPt = kp1 - kp2 * x3 - kp3 * x8;
        float Et   = (x3 > ke2) ? ke1 * (x3 - ke2) : 0.0f;
        float o3 = (fmaxf(EGPt, 0.0f) + Rat - Fsnc - Et - k1 * x3 + k2 * x4) *
                   (x3 >= 0.0f ? 1.0f : 0.0f);

        float Vmt  = Vm0 + Vmx * x6;
        float Uidt = Vmt * x4 / (Km0 + x4);
        float o4 = (-Uidt + k1 * x3 - k2 * x4) * (x4 >= 0.0f ? 1.0f : 0.0f);

        float o5 = (-(m2 + m4) * x5 + m1 * x9 + ka1 * x10 + ka2 * x11) *
                   (x5 >= 0.0f ? 1.0f : 0.0f);
        float It = x5 / Vi;
        float o6 = -p2u * x6 + p2u * (It - Ib);
        float o7 = -ki * (x7 - It);
        float o8 = -ki * (x8 - x7);
        float o9  = (-(m1 + m30) * x9 + m2 * x5) * (x9 >= 0.0f ? 1.0f : 0.0f);
        float o10 = (insulin - (ka1 + kd) * x10) * (x10 >= 0.0f ? 1.0f : 0.0f);
        float o11 = (kd * x10 - ka2 * x11) * (x11 >= 0.0f ? 1.0f : 0.0f);
        float o12 = (-ksc * x12 + ksc * x3) * (x12 >= 0.0f ? 1.0f : 0.0f);

        __syncthreads();   // all lanes done reading lds_x before overwrite

        float* o = lds_x + tid * NX;   // own row only, conflict-free
        o[0] = o0;  o[1] = o1;  o[2] = o2;  o[3] = o3;  o[4] = o4;
        o[5] = o5;  o[6] = o6;  o[7] = o7;  o[8] = o8;  o[9] = o9;
        o[10] = o10; o[11] = o11; o[12] = o12;
    } else {
        __syncthreads();   // keep barrier uniform across the block
    }
    __syncthreads();

    // ---- coalesced non-temporal float4 store of the contiguous chunk ----
    {
        float* dst = out + blockStart * NX;   // 16B aligned
        const int tot = nrows * NX;
        const int nf4 = tot >> 2;
        const v4f* s4 = (const v4f*)lds_x;
        v4f* d4 = (v4f*)dst;
        for (int idx = tid; idx < nf4; idx += ROWS)
            __builtin_nontemporal_store(s4[idx], d4 + idx);
        for (int g = (nf4 << 2) + tid; g < tot; g += ROWS)
            dst[g] = lds_x[g];
    }
}

extern "C" void kernel_launch(void* const* d_in, const int* in_sizes, int n_in,
                              void* d_out, int out_size, void* d_ws, size_t ws_size,
                              hipStream_t stream) {
    const float* x    = (const float*)d_in[0];
    const float* par  = (const float*)d_in[1];
    const float* CHO  = (const float*)d_in[2];
    const float* ins  = (const float*)d_in[3];
    const float* lq   = (const float*)d_in[4];
    const float* lf   = (const float*)d_in[5];
    float* out = (float*)d_out;
    int n = in_sizes[2];  // B (CHO length)

    int grid = (int)(((long long)n + ROWS - 1) / ROWS);
    t1d_kernel<<<grid, ROWS, 0, stream>>>(x, par, CHO, ins, lq, lf, out, n);
}

// Round 7
// 91.848 us; speedup vs baseline: 1.2086x; 1.2086x over previous
//
#include <hip/hip_runtime.h>
#include <math.h>

#define NP 30
#define NX 13
#define ROWS 256

typedef float v4f __attribute__((ext_vector_type(4)));

__global__ __launch_bounds__(ROWS) void t1d_kernel(
    const float* __restrict__ x,
    const float* __restrict__ params,
    const float* __restrict__ CHO,
    const float* __restrict__ insulin_u,
    const float* __restrict__ last_Qsto,
    const float* __restrict__ last_foodtaken,
    float* __restrict__ out,
    int n)
{
    // params staged via coalesced float4 (64% of read transactions), x read
    // scalar (proven fine at high occupancy in R5). The SAME LDS buffer is
    // reused for outputs (13.3KB < 30.7KB), keeping total LDS at 30720B ->
    // 5 blocks/CU = 20 waves. Writes: R5's proven full-line coalesced
    // non-temporal float4 path (ideal WRITE_SIZE, no L2/L3 pollution).
    __shared__ float lds_buf[ROWS * NP];   // 30720 B: params, then outputs

    const int tid = threadIdx.x;
    const long long blockStart = (long long)blockIdx.x * ROWS;
    const long long rem = (long long)n - blockStart;
    if (rem <= 0) return;
    const int nrows = rem < ROWS ? (int)rem : ROWS;

    // ---- stage params with fully-coalesced float4 loads ----
    {
        const float* srcp = params + blockStart * NP;   // 30720B*blockIdx -> 16B aligned
        const int totp = nrows * NP;
        const int pf4 = totp >> 2;
        const v4f* s4 = (const v4f*)srcp;
        v4f* d4 = (v4f*)lds_buf;
        for (int idx = tid; idx < pf4; idx += ROWS) d4[idx] = s4[idx];
        for (int g = (pf4 << 2) + tid; g < totp; g += ROWS) lds_buf[g] = srcp[g];
    }
    __syncthreads();

    float o0, o1, o2, o3, o4, o5, o6, o7, o8, o9, o10, o11, o12;
    if (tid < nrows) {
        const long long i = blockStart + tid;

        const float* p = lds_buf + tid * NP;   // stride-30: ~4 lanes/bank, ~1.6x, cheap
        float kmax = p[0],  kmin = p[1],  b    = p[2],  d_   = p[3];
        float kabs = p[4],  f    = p[5],  BW   = p[6],  kp1  = p[7];
        float kp2  = p[8],  kp3  = p[9],  Fsnc = p[10], ke1  = p[11];
        float ke2  = p[12], k1   = p[13], k2   = p[14], Vm0  = p[15];
        float Vmx  = p[16], Km0  = p[17], m1   = p[18], m2   = p[19];
        float m4   = p[20], m30  = p[21], ka1  = p[22], ka2  = p[23];
        float kd   = p[24], Vi   = p[25], p2u  = p[26], Ib   = p[27];
        float ki   = p[28], ksc  = p[29];

        const float* xr = x + i * NX;          // scalar reads, high-occupancy path
        float x0 = xr[0], x1 = xr[1], x2 = xr[2], x3 = xr[3], x4 = xr[4];
        float x5 = xr[5], x6 = xr[6], x7 = xr[7], x8 = xr[8], x9 = xr[9];
        float x10 = xr[10], x11 = xr[11], x12 = xr[12];

        float d       = CHO[i] * 1000.0f;               // stride-1 coalesced
        float insulin = insulin_u[i] * 6000.0f / BW;

        float qsto = x0 + x1;
        float Dbar = last_Qsto[i] + last_foodtaken[i];  // stride-1 coalesced
        bool has_food = Dbar > 0.0f;
        float Dbar_safe = has_food ? Dbar : 1.0f;
        float aa = 2.5f / (1.0f - b) / Dbar_safe;
        float cc = 2.5f / d_ / Dbar_safe;
        float kgut_eating = kmin + (kmax - kmin) * 0.5f *
            (tanhf(aa * (qsto - b * Dbar)) - tanhf(cc * (qsto - d_ * Dbar)) + 2.0f);
        float kgut = has_food ? kgut_eating : kmax;

        o0 = -kmax * x0 + d;
        o1 = kmax * x0 - x1 * kgut;
        o2 = kgut * x1 - kabs * x2;

        float Rat  = f * kabs * x2 / BW;
        float EGPt = kp1 - kp2 * x3 - kp3 * x8;
        float Et   = (x3 > ke2) ? ke1 * (x3 - ke2) : 0.0f;
        o3 = (fmaxf(EGPt, 0.0f) + Rat - Fsnc - Et - k1 * x3 + k2 * x4) *
             (x3 >= 0.0f ? 1.0f : 0.0f);

        float Vmt  = Vm0 + Vmx * x6;
        float Uidt = Vmt * x4 / (Km0 + x4);
        o4 = (-Uidt + k1 * x3 - k2 * x4) * (x4 >= 0.0f ? 1.0f : 0.0f);

        o5 = (-(m2 + m4) * x5 + m1 * x9 + ka1 * x10 + ka2 * x11) *
             (x5 >= 0.0f ? 1.0f : 0.0f);
        float It = x5 / Vi;
        o6 = -p2u * x6 + p2u * (It - Ib);
        o7 = -ki * (x7 - It);
        o8 = -ki * (x8 - x7);
        o9  = (-(m1 + m30) * x9 + m2 * x5) * (x9 >= 0.0f ? 1.0f : 0.0f);
        o10 = (insulin - (ka1 + kd) * x10) * (x10 >= 0.0f ? 1.0f : 0.0f);
        o11 = (kd * x10 - ka2 * x11) * (x11 >= 0.0f ? 1.0f : 0.0f);
        o12 = (-ksc * x12 + ksc * x3) * (x12 >= 0.0f ? 1.0f : 0.0f);
    }

    // everyone's params-reads from lds_buf are done before anyone overwrites
    __syncthreads();

    if (tid < nrows) {
        float* o = lds_buf + tid * NX;   // stride-13: conflict-free
        o[0] = o0;  o[1] = o1;  o[2] = o2;  o[3] = o3;  o[4] = o4;
        o[5] = o5;  o[6] = o6;  o[7] = o7;  o[8] = o8;  o[9] = o9;
        o[10] = o10; o[11] = o11; o[12] = o12;
    }
    __syncthreads();

    // ---- coalesced non-temporal float4 store of the contiguous chunk ----
    {
        float* dst = out + blockStart * NX;   // 13312B*blockIdx -> 16B aligned
        const int tot = nrows * NX;
        const int nf4 = tot >> 2;
        const v4f* s4 = (const v4f*)lds_buf;
        v4f* d4 = (v4f*)dst;
        for (int idx = tid; idx < nf4; idx += ROWS)
            __builtin_nontemporal_store(s4[idx], d4 + idx);
        for (int g = (nf4 << 2) + tid; g < tot; g += ROWS)
            dst[g] = lds_buf[g];
    }
}

extern "C" void kernel_launch(void* const* d_in, const int* in_sizes, int n_in,
                              void* d_out, int out_size, void* d_ws, size_t ws_size,
                              hipStream_t stream) {
    const float* x    = (const float*)d_in[0];
    const float* par  = (const float*)d_in[1];
    const float* CHO  = (const float*)d_in[2];
    const float* ins  = (const float*)d_in[3];
    const float* lq   = (const float*)d_in[4];
    const float* lf   = (const float*)d_in[5];
    float* out = (float*)d_out;
    int n = in_sizes[2];  // B (CHO length)

    int grid = (int)(((long long)n + ROWS - 1) / ROWS);
    t1d_kernel<<<grid, ROWS, 0, stream>>>(x, par, CHO, ins, lq, lf, out, n);
}

// Round 8
// 73.238 us; speedup vs baseline: 1.5158x; 1.2541x over previous
//
#include <hip/hip_runtime.h>
#include <math.h>

#define NP 30
#define NX 13
#define ROWS 256

typedef float v4f __attribute__((ext_vector_type(4)));

__global__ __launch_bounds__(ROWS) void t1d_kernel(
    const float* __restrict__ x,
    const float* __restrict__ params,
    const float* __restrict__ CHO,
    const float* __restrict__ insulin_u,
    const float* __restrict__ last_Qsto,
    const float* __restrict__ last_foodtaken,
    float* __restrict__ out,
    int n)
{
    // Cache-policy partition: x + scalar streams (128 MB/pass) are loaded
    // NON-TEMPORAL (sequential single-touch -> stream from HBM at full BW,
    // don't allocate in L2/L3), so the 240 MB params array fits entirely in
    // the 256 MiB L3 and stops re-fetching. Outputs: R5's proven full-line
    // coalesced nt float4 stores. LDS kept at 13.3 KB for high occupancy;
    // x-buffer is reused for outputs (each thread overwrites only its own
    // row -> no barrier between read and overwrite).
    __shared__ float lds_x[ROWS * NX];   // 13312 B: x rows, then outputs

    const int tid = threadIdx.x;
    const long long blockStart = (long long)blockIdx.x * ROWS;
    const long long rem = (long long)n - blockStart;
    if (rem <= 0) return;
    const int nrows = rem < ROWS ? (int)rem : ROWS;

    // ---- stage x with coalesced NON-TEMPORAL float4 loads ----
    {
        const float* srcx = x + blockStart * NX;        // 13312B*blockIdx -> 16B aligned
        const int totx = nrows * NX;
        const int xf4 = totx >> 2;
        const v4f* sx4 = (const v4f*)srcx;
        v4f* dx4 = (v4f*)lds_x;
        for (int idx = tid; idx < xf4; idx += ROWS)
            dx4[idx] = __builtin_nontemporal_load(sx4 + idx);
        for (int g = (xf4 << 2) + tid; g < totx; g += ROWS)
            lds_x[g] = __builtin_nontemporal_load(srcx + g);
    }
    __syncthreads();

    if (tid < nrows) {
        const long long i = blockStart + tid;

        const float* p = params + i * NP;   // NORMAL loads: let L3 keep all 240 MB
        float kmax = p[0],  kmin = p[1],  b    = p[2],  d_   = p[3];
        float kabs = p[4],  f    = p[5],  BW   = p[6],  kp1  = p[7];
        float kp2  = p[8],  kp3  = p[9],  Fsnc = p[10], ke1  = p[11];
        float ke2  = p[12], k1   = p[13], k2   = p[14], Vm0  = p[15];
        float Vmx  = p[16], Km0  = p[17], m1   = p[18], m2   = p[19];
        float m4   = p[20], m30  = p[21], ka1  = p[22], ka2  = p[23];
        float kd   = p[24], Vi   = p[25], p2u  = p[26], Ib   = p[27];
        float ki   = p[28], ksc  = p[29];

        const float* xr = lds_x + tid * NX;  // stride-13: conflict-free
        float x0 = xr[0], x1 = xr[1], x2 = xr[2], x3 = xr[3], x4 = xr[4];
        float x5 = xr[5], x6 = xr[6], x7 = xr[7], x8 = xr[8], x9 = xr[9];
        float x10 = xr[10], x11 = xr[11], x12 = xr[12];

        // scalar streams: single-touch, stride-1 -> non-temporal
        float cho = __builtin_nontemporal_load(CHO + i);
        float ins = __builtin_nontemporal_load(insulin_u + i);
        float lq  = __builtin_nontemporal_load(last_Qsto + i);
        float lf  = __builtin_nontemporal_load(last_foodtaken + i);

        float d       = cho * 1000.0f;
        float insulin = ins * 6000.0f / BW;

        float qsto = x0 + x1;
        float Dbar = lq + lf;
        bool has_food = Dbar > 0.0f;
        float Dbar_safe = has_food ? Dbar : 1.0f;
        float aa = 2.5f / (1.0f - b) / Dbar_safe;
        float cc = 2.5f / d_ / Dbar_safe;
        float kgut_eating = kmin + (kmax - kmin) * 0.5f *
            (tanhf(aa * (qsto - b * Dbar)) - tanhf(cc * (qsto - d_ * Dbar)) + 2.0f);
        float kgut = has_food ? kgut_eating : kmax;

        float o0 = -kmax * x0 + d;
        float o1 = kmax * x0 - x1 * kgut;
        float o2 = kgut * x1 - kabs * x2;

        float Rat  = f * kabs * x2 / BW;
        float EGPt = kp1 - kp2 * x3 - kp3 * x8;
        float Et   = (x3 > ke2) ? ke1 * (x3 - ke2) : 0.0f;
        float o3 = (fmaxf(EGPt, 0.0f) + Rat - Fsnc - Et - k1 * x3 + k2 * x4) *
                   (x3 >= 0.0f ? 1.0f : 0.0f);

        float Vmt  = Vm0 + Vmx * x6;
        float Uidt = Vmt * x4 / (Km0 + x4);
        float o4 = (-Uidt + k1 * x3 - k2 * x4) * (x4 >= 0.0f ? 1.0f : 0.0f);

        float o5 = (-(m2 + m4) * x5 + m1 * x9 + ka1 * x10 + ka2 * x11) *
                   (x5 >= 0.0f ? 1.0f : 0.0f);
        float It = x5 / Vi;
        float o6 = -p2u * x6 + p2u * (It - Ib);
        float o7 = -ki * (x7 - It);
        float o8 = -ki * (x8 - x7);
        float o9  = (-(m1 + m30) * x9 + m2 * x5) * (x9 >= 0.0f ? 1.0f : 0.0f);
        float o10 = (ins * 6000.0f / BW - (ka1 + kd) * x10) * (x10 >= 0.0f ? 1.0f : 0.0f);
        float o11 = (kd * x10 - ka2 * x11) * (x11 >= 0.0f ? 1.0f : 0.0f);
        float o12 = (-ksc * x12 + ksc * x3) * (x12 >= 0.0f ? 1.0f : 0.0f);
        (void)insulin;

        // overwrite OWN row only -> no barrier needed before this
        float* o = lds_x + tid * NX;
        o[0] = o0;  o[1] = o1;  o[2] = o2;  o[3] = o3;  o[4] = o4;
        o[5] = o5;  o[6] = o6;  o[7] = o7;  o[8] = o8;  o[9] = o9;
        o[10] = o10; o[11] = o11; o[12] = o12;
    }
    __syncthreads();

    // ---- coalesced non-temporal float4 store of the contiguous chunk ----
    {
        float* dst = out + blockStart * NX;   // 16B aligned
        const int tot = nrows * NX;
        const int nf4 = tot >> 2;
        const v4f* s4 = (const v4f*)lds_x;
        v4f* d4 = (v4f*)dst;
        for (int idx = tid; idx < nf4; idx += ROWS)
            __builtin_nontemporal_store(s4[idx], d4 + idx);
        for (int g = (nf4 << 2) + tid; g < tot; g += ROWS)
            dst[g] = lds_x[g];
    }
}

extern "C" void kernel_launch(void* const* d_in, const int* in_sizes, int n_in,
                              void* d_out, int out_size, void* d_ws, size_t ws_size,
                              hipStream_t stream) {
    const float* x    = (const float*)d_in[0];
    const float* par  = (const float*)d_in[1];
    const float* CHO  = (const float*)d_in[2];
    const float* ins  = (const float*)d_in[3];
    const float* lq   = (const float*)d_in[4];
    const float* lf   = (const float*)d_in[5];
    float* out = (float*)d_out;
    int n = in_sizes[2];  // B (CHO length)

    int grid = (int)(((long long)n + ROWS - 1) / ROWS);
    t1d_kernel<<<grid, ROWS, 0, stream>>>(x, par, CHO, ins, lq, lf, out, n);
}

// Round 9
// 73.080 us; speedup vs baseline: 1.5190x; 1.0022x over previous
//
#include <hip/hip_runtime.h>
#include <math.h>

#define NP 30
#define NX 13
#define ROWS 256

typedef float v4f __attribute__((ext_vector_type(4)));
typedef float v2f __attribute__((ext_vector_type(2)));

__global__ __launch_bounds__(ROWS) void t1d_kernel(
    const float* __restrict__ x,
    const float* __restrict__ params,
    const float* __restrict__ CHO,
    const float* __restrict__ insulin_u,
    const float* __restrict__ last_Qsto,
    const float* __restrict__ last_foodtaken,
    float* __restrict__ out,
    int n)
{
    // Policy partition (R8's win): x + scalar streams + output are
    // non-temporal (sequential single-touch, stream HBM, no L3 alloc) so the
    // 240 MB params array stays L3-resident. New in R9: params row read as
    // 15 float2 (rows are 8B-aligned: 120B stride) -> half the
    // scatter-address work of 30 scalar dword loads.
    __shared__ float lds_x[ROWS * NX];   // 13312 B: x rows, then outputs

    const int tid = threadIdx.x;
    const long long blockStart = (long long)blockIdx.x * ROWS;
    const long long rem = (long long)n - blockStart;
    if (rem <= 0) return;
    const int nrows = rem < ROWS ? (int)rem : ROWS;

    // ---- stage x with coalesced NON-TEMPORAL float4 loads ----
    {
        const float* srcx = x + blockStart * NX;        // 13312B*blockIdx -> 16B aligned
        const int totx = nrows * NX;
        const int xf4 = totx >> 2;
        const v4f* sx4 = (const v4f*)srcx;
        v4f* dx4 = (v4f*)lds_x;
        for (int idx = tid; idx < xf4; idx += ROWS)
            dx4[idx] = __builtin_nontemporal_load(sx4 + idx);
        for (int g = (xf4 << 2) + tid; g < totx; g += ROWS)
            lds_x[g] = __builtin_nontemporal_load(srcx + g);
    }
    __syncthreads();

    if (tid < nrows) {
        const long long i = blockStart + tid;

        // params: NORMAL (cached) float2 loads — 15 instrs instead of 30
        const v2f* pp = (const v2f*)(params + i * NP);  // 8B-aligned (i*120B)
        v2f q0  = pp[0],  q1  = pp[1],  q2  = pp[2],  q3  = pp[3],  q4  = pp[4];
        v2f q5  = pp[5],  q6  = pp[6],  q7  = pp[7],  q8  = pp[8],  q9  = pp[9];
        v2f q10 = pp[10], q11 = pp[11], q12 = pp[12], q13 = pp[13], q14 = pp[14];

        float kmax = q0[0],  kmin = q0[1],  b    = q1[0],  d_   = q1[1];
        float kabs = q2[0],  f    = q2[1],  BW   = q3[0],  kp1  = q3[1];
        float kp2  = q4[0],  kp3  = q4[1],  Fsnc = q5[0],  ke1  = q5[1];
        float ke2  = q6[0],  k1   = q6[1],  k2   = q7[0],  Vm0  = q7[1];
        float Vmx  = q8[0],  Km0  = q8[1],  m1   = q9[0],  m2   = q9[1];
        float m4   = q10[0], m30  = q10[1], ka1  = q11[0], ka2  = q11[1];
        float kd   = q12[0], Vi   = q12[1], p2u  = q13[0], Ib   = q13[1];
        float ki   = q14[0], ksc  = q14[1];

        const float* xr = lds_x + tid * NX;  // stride-13: conflict-free
        float x0 = xr[0], x1 = xr[1], x2 = xr[2], x3 = xr[3], x4 = xr[4];
        float x5 = xr[5], x6 = xr[6], x7 = xr[7], x8 = xr[8], x9 = xr[9];
        float x10 = xr[10], x11 = xr[11], x12 = xr[12];

        // scalar streams: single-touch, stride-1 -> non-temporal
        float cho = __builtin_nontemporal_load(CHO + i);
        float ins = __builtin_nontemporal_load(insulin_u + i);
        float lq  = __builtin_nontemporal_load(last_Qsto + i);
        float lf  = __builtin_nontemporal_load(last_foodtaken + i);

        float d       = cho * 1000.0f;
        float insulin = ins * 6000.0f / BW;

        float qsto = x0 + x1;
        float Dbar = lq + lf;
        bool has_food = Dbar > 0.0f;
        float Dbar_safe = has_food ? Dbar : 1.0f;
        float aa = 2.5f / (1.0f - b) / Dbar_safe;
        float cc = 2.5f / d_ / Dbar_safe;
        float kgut_eating = kmin + (kmax - kmin) * 0.5f *
            (tanhf(aa * (qsto - b * Dbar)) - tanhf(cc * (qsto - d_ * Dbar)) + 2.0f);
        float kgut = has_food ? kgut_eating : kmax;

        float o0 = -kmax * x0 + d;
        float o1 = kmax * x0 - x1 * kgut;
        float o2 = kgut * x1 - kabs * x2;

        float Rat  = f * kabs * x2 / BW;
        float EGPt = kp1 - kp2 * x3 - kp3 * x8;
        float Et   = (x3 > ke2) ? ke1 * (x3 - ke2) : 0.0f;
        float o3 = (fmaxf(EGPt, 0.0f) + Rat - Fsnc - Et - k1 * x3 + k2 * x4) *
                   (x3 >= 0.0f ? 1.0f : 0.0f);

        float Vmt  = Vm0 + Vmx * x6;
        float Uidt = Vmt * x4 / (Km0 + x4);
        float o4 = (-Uidt + k1 * x3 - k2 * x4) * (x4 >= 0.0f ? 1.0f : 0.0f);

        float o5 = (-(m2 + m4) * x5 + m1 * x9 + ka1 * x10 + ka2 * x11) *
                   (x5 >= 0.0f ? 1.0f : 0.0f);
        float It = x5 / Vi;
        float o6 = -p2u * x6 + p2u * (It - Ib);
        float o7 = -ki * (x7 - It);
        float o8 = -ki * (x8 - x7);
        float o9  = (-(m1 + m30) * x9 + m2 * x5) * (x9 >= 0.0f ? 1.0f : 0.0f);
        float o10 = (insulin - (ka1 + kd) * x10) * (x10 >= 0.0f ? 1.0f : 0.0f);
        float o11 = (kd * x10 - ka2 * x11) * (x11 >= 0.0f ? 1.0f : 0.0f);
        float o12 = (-ksc * x12 + ksc * x3) * (x12 >= 0.0f ? 1.0f : 0.0f);

        // overwrite OWN row only -> no barrier needed before this
        float* o = lds_x + tid * NX;
        o[0] = o0;  o[1] = o1;  o[2] = o2;  o[3] = o3;  o[4] = o4;
        o[5] = o5;  o[6] = o6;  o[7] = o7;  o[8] = o8;  o[9] = o9;
        o[10] = o10; o[11] = o11; o[12] = o12;
    }
    __syncthreads();

    // ---- coalesced non-temporal float4 store of the contiguous chunk ----
    {
        float* dst = out + blockStart * NX;   // 16B aligned
        const int tot = nrows * NX;
        const int nf4 = tot >> 2;
        const v4f* s4 = (const v4f*)lds_x;
        v4f* d4 = (v4f*)dst;
        for (int idx = tid; idx < nf4; idx += ROWS)
            __builtin_nontemporal_store(s4[idx], d4 + idx);
        for (int g = (nf4 << 2) + tid; g < tot; g += ROWS)
            dst[g] = lds_x[g];
    }
}

extern "C" void kernel_launch(void* const* d_in, const int* in_sizes, int n_in,
                              void* d_out, int out_size, void* d_ws, size_t ws_size,
                              hipStream_t stream) {
    const float* x    = (const float*)d_in[0];
    const float* par  = (const float*)d_in[1];
    const float* CHO  = (const float*)d_in[2];
    const float* ins  = (const float*)d_in[3];
    const float* lq   = (const float*)d_in[4];
    const float* lf   = (const float*)d_in[5];
    float* out = (float*)d_out;
    int n = in_sizes[2];  // B (CHO length)

    int grid = (int)(((long long)n + ROWS - 1) / ROWS);
    t1d_kernel<<<grid, ROWS, 0, stream>>>(x, par, CHO, ins, lq, lf, out, n);
}